// Round 6
// baseline (123.426 us; speedup 1.0000x reference)
//
#include <hip/hip_runtime.h>

// ---- types ----
typedef __bf16 bf16x8 __attribute__((ext_vector_type(8)));
typedef __bf16 bf16x4 __attribute__((ext_vector_type(4)));
typedef short s16x4 __attribute__((ext_vector_type(4)));
typedef float f32x4 __attribute__((ext_vector_type(4)));

#define MFMA32(a, b, c) __builtin_amdgcn_mfma_f32_16x16x32_bf16((a), (b), (c), 0, 0, 0)
#define MFMA16(a, b, c) __builtin_amdgcn_mfma_f32_16x16x16bf16_1k((a), (b), (c), 0, 0, 0)

// q pre-scale: 1/sqrt(E)=0.25 folded with 1/ln(2) so attn uses exp2 directly.
#define QSCALE 0.36067376022224085f

static __device__ inline bf16x8 cvt8(float4 a, float4 b) {
    bf16x8 r;
    r[0] = (__bf16)a.x; r[1] = (__bf16)a.y; r[2] = (__bf16)a.z; r[3] = (__bf16)a.w;
    r[4] = (__bf16)b.x; r[5] = (__bf16)b.y; r[6] = (__bf16)b.z; r[7] = (__bf16)b.w;
    return r;
}

// Grid-wide barrier for a persistent kernel (256 blocks = 1/CU, co-resident by
// capacity).  Device-scope atomics + threadfence for cross-XCD visibility.
// Counters are zeroed each launch by a hipMemsetAsync node before the kernel.
// Bounded spin: if co-residency ever failed we break (wrong answer, no hang).
static __device__ inline void grid_barrier(unsigned* cnt, int nblk) {
    __syncthreads();
    if (threadIdx.x == 0) {
        __threadfence();
        unsigned prev = __hip_atomic_fetch_add(cnt, 1u, __ATOMIC_ACQ_REL,
                                               __HIP_MEMORY_SCOPE_AGENT);
        if ((int)prev + 1 < nblk) {
            int guard = 0;
            while (__hip_atomic_load(cnt, __ATOMIC_ACQUIRE,
                                     __HIP_MEMORY_SCOPE_AGENT) < (unsigned)nblk) {
                __builtin_amdgcn_s_sleep(8);
                if (++guard > (1 << 22)) break;   // failsafe: never deadlock
            }
        }
        __threadfence();
    }
    __syncthreads();
}

// ============================================================================
// Fully fused persistent kernel: grid = 256 blocks x 512 threads.
//  P1 qkv:   block = 16 tokens; x tile staged to LDS (x read once, coalesced);
//            6 waves = (q,k,v) x (K-half 320); LDS reduce; q/k/v stores.
//  P2 attn:  block = (head, 64 q-tokens); wave = 512-kv chunk; depth-4 reg
//            pipeline on K/V (L2-resident); exp2, lsum via ones-MFMA; in-block
//            KV-combine + residual -> tiled voutT.
//  P3 dsgemm: block = (64 rows, K/8 chunk); 8 waves = 4 rowsubs x 2 K-halves;
//            LDS pair-reduce -> partial[8][2048][64];
//  P4 reduce: 131072 threads sum 8 partials + bias -> out.
// ============================================================================
__global__ __launch_bounds__(512) void fused_kernel(
    const float* __restrict__ x,
    const float* __restrict__ Wq, const float* __restrict__ bq,
    const float* __restrict__ Wk, const float* __restrict__ bk,
    const float* __restrict__ Wv, const float* __restrict__ bv,
    const float* __restrict__ Wd, const float* __restrict__ bd,
    __bf16* __restrict__ q_bf, __bf16* __restrict__ k_bf,
    __bf16* __restrict__ vT_t, __bf16* __restrict__ voutT,
    float* __restrict__ partial, unsigned* __restrict__ bars,
    float* __restrict__ out)
{
    __shared__ __align__(16) char arena[67584];

    const int tid = threadIdx.x;
    const int w = tid >> 6;
    const int lane = tid & 63;
    const int c = lane & 15;
    const int g = lane >> 4;

    // ------------------------------------------------------------ P1: QKV
    {
        const int rg = blockIdx.x;
        const int row0 = rg << 4;
        float* xs = (float*)arena;                       // [16][644] padded
        f32x4* red = (f32x4*)(arena + 41216);            // [6][4][64]

        const float4* xg = (const float4*)(x + row0 * 640);
        #pragma unroll
        for (int i = 0; i < 5; ++i) {
            const int j = tid + (i << 9);                // < 2560
            const int row = j / 160, col = j - row * 160;
            *(float4*)&xs[row * 644 + (col << 2)] = xg[j];
        }
        __syncthreads();

        if (w < 6) {
            const int which = w >> 1, kh = w & 1;
            const float* Wsel = which == 0 ? Wq : which == 1 ? Wk : Wv;
            const float* wr0 = Wsel + (0 * 16 + c) * 640 + kh * 320;
            const float* wr1 = Wsel + (1 * 16 + c) * 640 + kh * 320;
            const float* wr2 = Wsel + (2 * 16 + c) * 640 + kh * 320;
            const float* wr3 = Wsel + (3 * 16 + c) * 640 + kh * 320;
            const float* xr = xs + c * 644 + kh * 320;

            f32x4 acc0 = {0.f,0.f,0.f,0.f}, acc1 = acc0, acc2 = acc0, acc3 = acc0;
            #pragma unroll 2
            for (int it = 0; it < 10; ++it) {
                const int kk = (it << 5) + (g << 3);
                bf16x8 af = cvt8(*(const float4*)(xr + kk), *(const float4*)(xr + kk + 4));
                bf16x8 b0 = cvt8(*(const float4*)(wr0 + kk), *(const float4*)(wr0 + kk + 4));
                bf16x8 b1 = cvt8(*(const float4*)(wr1 + kk), *(const float4*)(wr1 + kk + 4));
                bf16x8 b2 = cvt8(*(const float4*)(wr2 + kk), *(const float4*)(wr2 + kk + 4));
                bf16x8 b3 = cvt8(*(const float4*)(wr3 + kk), *(const float4*)(wr3 + kk + 4));
                acc0 = MFMA32(af, b0, acc0);
                acc1 = MFMA32(af, b1, acc1);
                acc2 = MFMA32(af, b2, acc2);
                acc3 = MFMA32(af, b3, acc3);
            }
            red[((w << 2) + 0) * 64 + lane] = acc0;
            red[((w << 2) + 1) * 64 + lane] = acc1;
            red[((w << 2) + 2) * 64 + lane] = acc2;
            red[((w << 2) + 3) * 64 + lane] = acc3;
        }
        __syncthreads();

        #pragma unroll
        for (int pass = 0; pass < 2; ++pass) {
            const int s = tid + (pass << 9);
            if (s < 768) {
                const int which = s >> 8;
                const int h = (s >> 6) & 3;
                const int ln = s & 63;
                const int cc = ln & 15, gg = ln >> 4;
                f32x4 sum = red[(((which << 1) << 2) + h) * 64 + ln]
                          + red[((((which << 1) + 1) << 2) + h) * 64 + ln];
                const float* bsel = which == 0 ? bq : which == 1 ? bk : bv;
                const float bias = bsel[(h << 4) + cc];
                if (which == 2) {
                    bf16x4 vv;
                    #pragma unroll
                    for (int i = 0; i < 4; ++i) vv[i] = (__bf16)(sum[i] + bias);
                    *(bf16x4*)(vT_t + ((((h << 8) + rg) << 8) + (cc << 4) + (gg << 2))) = vv;
                } else {
                    #pragma unroll
                    for (int i = 0; i < 4; ++i) {
                        const int n = row0 + (gg << 2) + i;
                        const float val = sum[i] + bias;
                        if (which == 0) q_bf[(((h << 12) + n) << 4) + cc] = (__bf16)(val * QSCALE);
                        else            k_bf[(((h << 12) + n) << 4) + cc] = (__bf16)val;
                    }
                }
            }
        }
    }
    grid_barrier(bars + 0, 256);

    // ------------------------------------------------------------ P2: attention
    {
        const int h = blockIdx.x >> 6;
        const int qblk = blockIdx.x & 63;           // 64 tokens
        float* accl = (float*)arena;                // [8][4][256] = 32 KB
        float* lred = (float*)(arena + 32768);      // [8][4][16]
        float* ltot = (float*)(arena + 34816);      // [4][16]

        const int qt0 = qblk << 2;
        const __bf16* qb = q_bf + (h << 16) + (((qblk << 6) + c) << 4) + (g << 2);
        const s16x4 qf0 = *(const s16x4*)(qb);
        const s16x4 qf1 = *(const s16x4*)(qb + 256);
        const s16x4 qf2 = *(const s16x4*)(qb + 512);
        const s16x4 qf3 = *(const s16x4*)(qb + 768);

        const __bf16* kb = k_bf + (h << 16) + (w << 13) + (c << 4) + (g << 2);
        const __bf16* vb = vT_t + (h << 16) + (w << 13) + (c << 4) + (g << 2);

        bf16x4 one4;
        #pragma unroll
        for (int j = 0; j < 4; ++j) one4[j] = (__bf16)1.0f;
        const s16x4 onesf = __builtin_bit_cast(s16x4, one4);

        const f32x4 z = {0.f, 0.f, 0.f, 0.f};
        f32x4 acc0 = z, acc1 = z, acc2 = z, acc3 = z;
        f32x4 la0 = z, la1 = z, la2 = z, la3 = z;

        s16x4 kr0 = *(const s16x4*)(kb);
        s16x4 kr1 = *(const s16x4*)(kb + 256);
        s16x4 kr2 = *(const s16x4*)(kb + 512);
        s16x4 kr3 = *(const s16x4*)(kb + 768);
        s16x4 vr0 = *(const s16x4*)(vb);
        s16x4 vr1 = *(const s16x4*)(vb + 256);
        s16x4 vr2 = *(const s16x4*)(vb + 512);
        s16x4 vr3 = *(const s16x4*)(vb + 768);

#define TILE_OP(QF, ACC, LA, KC, VC)                                          \
        {                                                                     \
            f32x4 s_ = MFMA16((KC), (QF), z);                                 \
            float p0 = __builtin_amdgcn_exp2f(s_[0]);                         \
            float p1 = __builtin_amdgcn_exp2f(s_[1]);                         \
            float p2 = __builtin_amdgcn_exp2f(s_[2]);                         \
            float p3 = __builtin_amdgcn_exp2f(s_[3]);                         \
            bf16x4 pb;                                                        \
            pb[0] = (__bf16)p0; pb[1] = (__bf16)p1;                           \
            pb[2] = (__bf16)p2; pb[3] = (__bf16)p3;                           \
            const s16x4 pf = __builtin_bit_cast(s16x4, pb);                   \
            (LA)  = MFMA16(onesf, pf, (LA));                                  \
            (ACC) = MFMA16((VC), pf, (ACC));                                  \
        }
#define ATTN_BODY(KC, VC)                                                     \
        TILE_OP(qf0, acc0, la0, KC, VC)                                       \
        TILE_OP(qf1, acc1, la1, KC, VC)                                       \
        TILE_OP(qf2, acc2, la2, KC, VC)                                       \
        TILE_OP(qf3, acc3, la3, KC, VC)

        for (int tt = 0; tt < 32; tt += 4) {
            s16x4 kc, vc;
            kc = kr0; vc = vr0;
            if (tt + 4 < 32) { kr0 = *(const s16x4*)(kb + ((tt + 4) << 8)); vr0 = *(const s16x4*)(vb + ((tt + 4) << 8)); }
            ATTN_BODY(kc, vc)
            kc = kr1; vc = vr1;
            if (tt + 5 < 32) { kr1 = *(const s16x4*)(kb + ((tt + 5) << 8)); vr1 = *(const s16x4*)(vb + ((tt + 5) << 8)); }
            ATTN_BODY(kc, vc)
            kc = kr2; vc = vr2;
            if (tt + 6 < 32) { kr2 = *(const s16x4*)(kb + ((tt + 6) << 8)); vr2 = *(const s16x4*)(vb + ((tt + 6) << 8)); }
            ATTN_BODY(kc, vc)
            kc = kr3; vc = vr3;
            if (tt + 7 < 32) { kr3 = *(const s16x4*)(kb + ((tt + 7) << 8)); vr3 = *(const s16x4*)(vb + ((tt + 7) << 8)); }
            ATTN_BODY(kc, vc)
        }
#undef ATTN_BODY
#undef TILE_OP

        *(f32x4*)&accl[(((w << 2) + 0) << 8) + (lane << 2)] = acc0;
        *(f32x4*)&accl[(((w << 2) + 1) << 8) + (lane << 2)] = acc1;
        *(f32x4*)&accl[(((w << 2) + 2) << 8) + (lane << 2)] = acc2;
        *(f32x4*)&accl[(((w << 2) + 3) << 8) + (lane << 2)] = acc3;
        if (g == 0) {
            lred[(((w << 2) + 0) << 4) + c] = la0[0];
            lred[(((w << 2) + 1) << 4) + c] = la1[0];
            lred[(((w << 2) + 2) << 4) + c] = la2[0];
            lred[(((w << 2) + 3) << 4) + c] = la3[0];
        }
        __syncthreads();

        if (tid < 64) {
            const int tile = tid >> 4, cc2 = tid & 15;
            float s = 0.f;
            #pragma unroll
            for (int w2 = 0; w2 < 8; ++w2) s += lred[(((w2 << 2) + tile) << 4) + cc2];
            ltot[tid] = 1.0f / s;
        }
        __syncthreads();

        #pragma unroll
        for (int pass = 0; pass < 2; ++pass) {
            const int s = tid + (pass << 9);         // < 1024
            const int tile = s >> 8, elem = s & 255;
            const int lane2 = elem >> 2, ii = elem & 3;
            const int c2 = lane2 & 15, g2 = lane2 >> 4;
            const int e = (g2 << 2) + ii;
            float ssum = 0.f;
            #pragma unroll
            for (int w2 = 0; w2 < 8; ++w2) ssum += accl[(((w2 << 2) + tile) << 8) + elem];
            const int qt = qt0 + tile;
            const float res = (float)vT_t[(((h << 8) + qt) << 8) + (e << 4) + c2];
            const float val = ssum * ltot[(tile << 4) + c2] + res;
            voutT[((qt >> 1) << 11) + (((h << 4) + e) << 5) + ((qt & 1) << 4) + c2] = (__bf16)val;
        }
    }
    grid_barrier(bars + 16, 256);

    // ------------------------------------------------------------ P3: ds GEMM
    {
        const int rb = blockIdx.x >> 3;              // 0..31  (64-row block)
        const int ks = blockIdx.x & 7;               // K chunk of 512
        const int rsub = w >> 1, kh = w & 1;
        const int r0 = (rb << 6) + (rsub << 4);
        const int kb0 = (ks << 9) + (kh << 8);
        const float* wdrow = Wd + (r0 + c) * 4096 + kb0;

        f32x4 acc0 = {0.f,0.f,0.f,0.f}, acc1 = acc0, acc2 = acc0, acc3 = acc0;
        #pragma unroll
        for (int it = 0; it < 8; ++it) {
            const int k0 = it << 5;
            bf16x8 af = cvt8(*(const float4*)(wdrow + k0 + (g << 3)),
                             *(const float4*)(wdrow + k0 + (g << 3) + 4));
            const __bf16* bt = voutT + (((kb0 + k0) >> 5) << 11) + (g << 3);
            bf16x8 b0 = *(const bf16x8*)(bt + ((c     ) << 5));
            bf16x8 b1 = *(const bf16x8*)(bt + ((c + 16) << 5));
            bf16x8 b2 = *(const bf16x8*)(bt + ((c + 32) << 5));
            bf16x8 b3 = *(const bf16x8*)(bt + ((c + 48) << 5));
            acc0 = MFMA32(af, b0, acc0);
            acc1 = MFMA32(af, b1, acc1);
            acc2 = MFMA32(af, b2, acc2);
            acc3 = MFMA32(af, b3, acc3);
        }

        float* dsred = (float*)arena;                // [4][4][64][4] = 16 KB
        if (kh == 1) {
            *(f32x4*)&dsred[(((rsub << 2) + 0) << 8) + (lane << 2)] = acc0;
            *(f32x4*)&dsred[(((rsub << 2) + 1) << 8) + (lane << 2)] = acc1;
            *(f32x4*)&dsred[(((rsub << 2) + 2) << 8) + (lane << 2)] = acc2;
            *(f32x4*)&dsred[(((rsub << 2) + 3) << 8) + (lane << 2)] = acc3;
        }
        __syncthreads();
        if (kh == 0) {
            acc0 += *(const f32x4*)&dsred[(((rsub << 2) + 0) << 8) + (lane << 2)];
            acc1 += *(const f32x4*)&dsred[(((rsub << 2) + 1) << 8) + (lane << 2)];
            acc2 += *(const f32x4*)&dsred[(((rsub << 2) + 2) << 8) + (lane << 2)];
            acc3 += *(const f32x4*)&dsred[(((rsub << 2) + 3) << 8) + (lane << 2)];
            float* pbase = partial + (((ks << 11) + r0) << 6);
            #pragma unroll
            for (int i = 0; i < 4; ++i) {
                const int r = (g << 2) + i;
                pbase[(r << 6) +      c] = acc0[i];
                pbase[(r << 6) + 16 + c] = acc1[i];
                pbase[(r << 6) + 32 + c] = acc2[i];
                pbase[(r << 6) + 48 + c] = acc3[i];
            }
        }
    }
    grid_barrier(bars + 32, 256);

    // ------------------------------------------------------------ P4: reduce
    {
        const int idx = (blockIdx.x << 9) + tid;     // < 131072
        float s = bd[idx >> 6];
        #pragma unroll
        for (int k = 0; k < 8; ++k) s += partial[(k << 17) + idx];
        out[idx] = s;
    }
}

// ============================================================================
extern "C" void kernel_launch(void* const* d_in, const int* in_sizes, int n_in,
                              void* d_out, int out_size, void* d_ws, size_t ws_size,
                              hipStream_t stream)
{
    const float* x  = (const float*)d_in[0];
    const float* Wq = (const float*)d_in[1];
    const float* bq = (const float*)d_in[2];
    const float* Wk = (const float*)d_in[3];
    const float* bk = (const float*)d_in[4];
    const float* Wv = (const float*)d_in[5];
    const float* bv = (const float*)d_in[6];
    const float* Wd = (const float*)d_in[7];
    const float* bd = (const float*)d_in[8];
    float* out = (float*)d_out;

    char* ws = (char*)d_ws;
    __bf16* q_bf   = (__bf16*)(ws);                  // 512 KB [4][4096][16]
    __bf16* k_bf   = (__bf16*)(ws + (1u << 19));     // 512 KB [4][4096][16]
    __bf16* vT_t   = (__bf16*)(ws + (2u << 19));     // 512 KB [4][256][16][16]
    __bf16* voutT  = (__bf16*)(ws + (3u << 19));     // 512 KB [128][64][32]
    float*  partial = (float*)(ws + (4u << 19));     // 4 MB  [8][2048][64]
    unsigned* bars  = (unsigned*)(ws + (12u << 19)); // barrier counters

    hipMemsetAsync(bars, 0, 256, stream);
    fused_kernel<<<dim3(256), dim3(512), 0, stream>>>(
        x, Wq, bq, Wk, bk, Wv, bv, Wd, bd,
        q_bf, k_bf, vT_t, voutT, partial, bars, out);
}

// Round 7
// 108.123 us; speedup vs baseline: 1.1415x; 1.1415x over previous
//
#include <hip/hip_runtime.h>

// ---- types ----
typedef __bf16 bf16x8 __attribute__((ext_vector_type(8)));
typedef __bf16 bf16x4 __attribute__((ext_vector_type(4)));
typedef short s16x4 __attribute__((ext_vector_type(4)));
typedef float f32x4 __attribute__((ext_vector_type(4)));

#define MFMA32(a, b, c) __builtin_amdgcn_mfma_f32_16x16x32_bf16((a), (b), (c), 0, 0, 0)
#define MFMA16(a, b, c) __builtin_amdgcn_mfma_f32_16x16x16bf16_1k((a), (b), (c), 0, 0, 0)

// q pre-scale: 1/sqrt(E)=0.25 folded with 1/ln(2) so attn uses exp2 directly.
#define QSCALE 0.36067376022224085f

static __device__ inline bf16x8 cvt8(float4 a, float4 b) {
    bf16x8 r;
    r[0] = (__bf16)a.x; r[1] = (__bf16)a.y; r[2] = (__bf16)a.z; r[3] = (__bf16)a.w;
    r[4] = (__bf16)b.x; r[5] = (__bf16)b.y; r[6] = (__bf16)b.z; r[7] = (__bf16)b.w;
    return r;
}

// Grid-wide barrier for a persistent kernel (256 blocks = 1/CU, co-resident).
// CRITICAL (round-6 lesson): the spin loop must poll with RELAXED agent-scope
// loads.  An ACQUIRE load in the loop emits an L1+L2 invalidate PER POLL on
// gfx950 (per-XCD L2s, coherence point = L3), which continuously flushes all
// caches for the whole barrier window (~35us/barrier observed).  Relaxed
// agent atomics bypass L2 to the coherence point, see remote updates, and
// invalidate nothing.  Exactly one release fence before signal, one acquire
// fence after exit.  Bounded spin: never deadlock, fail loud in absmax.
static __device__ inline void grid_barrier(unsigned* cnt, int nblk) {
    __syncthreads();
    if (threadIdx.x == 0) {
        __threadfence();   // release: write back this XCD's L2 once
        __hip_atomic_fetch_add(cnt, 1u, __ATOMIC_RELAXED,
                               __HIP_MEMORY_SCOPE_AGENT);
        int guard = 0;
        while (__hip_atomic_load(cnt, __ATOMIC_RELAXED,
                                 __HIP_MEMORY_SCOPE_AGENT) < (unsigned)nblk) {
            __builtin_amdgcn_s_sleep(4);
            if (++guard > (1 << 22)) break;   // failsafe: never hang
        }
        __threadfence();   // acquire: invalidate L1/L2 once
    }
    __syncthreads();
}

// ============================================================================
// Fully fused persistent kernel: grid = 256 blocks x 512 threads.
//  P1 qkv:   block = 16 tokens; x tile staged to LDS (x read once, coalesced);
//            6 waves = (q,k,v) x (K-half 320); LDS reduce; q/k/v stores.
//  P2 attn:  block = (head, 64 q-tokens); wave = 512-kv chunk; depth-4 reg
//            pipeline on K/V (L2/L3-resident); exp2, lsum via ones-MFMA;
//            in-block KV-combine + residual -> tiled voutT.
//  P3 dsgemm: block = (64 rows, K/8 chunk); 8 waves = 4 rowsubs x 2 K-halves;
//            LDS pair-reduce -> partial[8][2048][64];
//  P4 reduce: 131072 threads sum 8 partials + bias -> out.
// ============================================================================
__global__ __launch_bounds__(512) void fused_kernel(
    const float* __restrict__ x,
    const float* __restrict__ Wq, const float* __restrict__ bq,
    const float* __restrict__ Wk, const float* __restrict__ bk,
    const float* __restrict__ Wv, const float* __restrict__ bv,
    const float* __restrict__ Wd, const float* __restrict__ bd,
    __bf16* __restrict__ q_bf, __bf16* __restrict__ k_bf,
    __bf16* __restrict__ vT_t, __bf16* __restrict__ voutT,
    float* __restrict__ partial, unsigned* __restrict__ bars,
    float* __restrict__ out)
{
    __shared__ __align__(16) char arena[67584];

    const int tid = threadIdx.x;
    const int w = tid >> 6;
    const int lane = tid & 63;
    const int c = lane & 15;
    const int g = lane >> 4;

    // ------------------------------------------------------------ P1: QKV
    {
        const int rg = blockIdx.x;
        const int row0 = rg << 4;
        float* xs = (float*)arena;                       // [16][644] padded
        f32x4* red = (f32x4*)(arena + 41216);            // [6][4][64]

        const float4* xg = (const float4*)(x + row0 * 640);
        #pragma unroll
        for (int i = 0; i < 5; ++i) {
            const int j = tid + (i << 9);                // < 2560
            const int row = j / 160, col = j - row * 160;
            *(float4*)&xs[row * 644 + (col << 2)] = xg[j];
        }
        __syncthreads();

        if (w < 6) {
            const int which = w >> 1, kh = w & 1;
            const float* Wsel = which == 0 ? Wq : which == 1 ? Wk : Wv;
            const float* wr0 = Wsel + (0 * 16 + c) * 640 + kh * 320;
            const float* wr1 = Wsel + (1 * 16 + c) * 640 + kh * 320;
            const float* wr2 = Wsel + (2 * 16 + c) * 640 + kh * 320;
            const float* wr3 = Wsel + (3 * 16 + c) * 640 + kh * 320;
            const float* xr = xs + c * 644 + kh * 320;

            f32x4 acc0 = {0.f,0.f,0.f,0.f}, acc1 = acc0, acc2 = acc0, acc3 = acc0;
            #pragma unroll 2
            for (int it = 0; it < 10; ++it) {
                const int kk = (it << 5) + (g << 3);
                bf16x8 af = cvt8(*(const float4*)(xr + kk), *(const float4*)(xr + kk + 4));
                bf16x8 b0 = cvt8(*(const float4*)(wr0 + kk), *(const float4*)(wr0 + kk + 4));
                bf16x8 b1 = cvt8(*(const float4*)(wr1 + kk), *(const float4*)(wr1 + kk + 4));
                bf16x8 b2 = cvt8(*(const float4*)(wr2 + kk), *(const float4*)(wr2 + kk + 4));
                bf16x8 b3 = cvt8(*(const float4*)(wr3 + kk), *(const float4*)(wr3 + kk + 4));
                acc0 = MFMA32(af, b0, acc0);
                acc1 = MFMA32(af, b1, acc1);
                acc2 = MFMA32(af, b2, acc2);
                acc3 = MFMA32(af, b3, acc3);
            }
            red[((w << 2) + 0) * 64 + lane] = acc0;
            red[((w << 2) + 1) * 64 + lane] = acc1;
            red[((w << 2) + 2) * 64 + lane] = acc2;
            red[((w << 2) + 3) * 64 + lane] = acc3;
        }
        __syncthreads();

        #pragma unroll
        for (int pass = 0; pass < 2; ++pass) {
            const int s = tid + (pass << 9);
            if (s < 768) {
                const int which = s >> 8;
                const int h = (s >> 6) & 3;
                const int ln = s & 63;
                const int cc = ln & 15, gg = ln >> 4;
                f32x4 sum = red[(((which << 1) << 2) + h) * 64 + ln]
                          + red[((((which << 1) + 1) << 2) + h) * 64 + ln];
                const float* bsel = which == 0 ? bq : which == 1 ? bk : bv;
                const float bias = bsel[(h << 4) + cc];
                if (which == 2) {
                    bf16x4 vv;
                    #pragma unroll
                    for (int i = 0; i < 4; ++i) vv[i] = (__bf16)(sum[i] + bias);
                    *(bf16x4*)(vT_t + ((((h << 8) + rg) << 8) + (cc << 4) + (gg << 2))) = vv;
                } else {
                    #pragma unroll
                    for (int i = 0; i < 4; ++i) {
                        const int n = row0 + (gg << 2) + i;
                        const float val = sum[i] + bias;
                        if (which == 0) q_bf[(((h << 12) + n) << 4) + cc] = (__bf16)(val * QSCALE);
                        else            k_bf[(((h << 12) + n) << 4) + cc] = (__bf16)val;
                    }
                }
            }
        }
    }
    grid_barrier(bars + 0, 256);

    // ------------------------------------------------------------ P2: attention
    {
        const int h = blockIdx.x >> 6;
        const int qblk = blockIdx.x & 63;           // 64 tokens
        float* accl = (float*)arena;                // [8][4][256] = 32 KB
        float* lred = (float*)(arena + 32768);      // [8][4][16]
        float* ltot = (float*)(arena + 34816);      // [4][16]

        const int qt0 = qblk << 2;
        const __bf16* qb = q_bf + (h << 16) + (((qblk << 6) + c) << 4) + (g << 2);
        const s16x4 qf0 = *(const s16x4*)(qb);
        const s16x4 qf1 = *(const s16x4*)(qb + 256);
        const s16x4 qf2 = *(const s16x4*)(qb + 512);
        const s16x4 qf3 = *(const s16x4*)(qb + 768);

        const __bf16* kb = k_bf + (h << 16) + (w << 13) + (c << 4) + (g << 2);
        const __bf16* vb = vT_t + (h << 16) + (w << 13) + (c << 4) + (g << 2);

        bf16x4 one4;
        #pragma unroll
        for (int j = 0; j < 4; ++j) one4[j] = (__bf16)1.0f;
        const s16x4 onesf = __builtin_bit_cast(s16x4, one4);

        const f32x4 z = {0.f, 0.f, 0.f, 0.f};
        f32x4 acc0 = z, acc1 = z, acc2 = z, acc3 = z;
        f32x4 la0 = z, la1 = z, la2 = z, la3 = z;

        s16x4 kr0 = *(const s16x4*)(kb);
        s16x4 kr1 = *(const s16x4*)(kb + 256);
        s16x4 kr2 = *(const s16x4*)(kb + 512);
        s16x4 kr3 = *(const s16x4*)(kb + 768);
        s16x4 vr0 = *(const s16x4*)(vb);
        s16x4 vr1 = *(const s16x4*)(vb + 256);
        s16x4 vr2 = *(const s16x4*)(vb + 512);
        s16x4 vr3 = *(const s16x4*)(vb + 768);

#define TILE_OP(QF, ACC, LA, KC, VC)                                          \
        {                                                                     \
            f32x4 s_ = MFMA16((KC), (QF), z);                                 \
            float p0 = __builtin_amdgcn_exp2f(s_[0]);                         \
            float p1 = __builtin_amdgcn_exp2f(s_[1]);                         \
            float p2 = __builtin_amdgcn_exp2f(s_[2]);                         \
            float p3 = __builtin_amdgcn_exp2f(s_[3]);                         \
            bf16x4 pb;                                                        \
            pb[0] = (__bf16)p0; pb[1] = (__bf16)p1;                           \
            pb[2] = (__bf16)p2; pb[3] = (__bf16)p3;                           \
            const s16x4 pf = __builtin_bit_cast(s16x4, pb);                   \
            (LA)  = MFMA16(onesf, pf, (LA));                                  \
            (ACC) = MFMA16((VC), pf, (ACC));                                  \
        }
#define ATTN_BODY(KC, VC)                                                     \
        TILE_OP(qf0, acc0, la0, KC, VC)                                       \
        TILE_OP(qf1, acc1, la1, KC, VC)                                       \
        TILE_OP(qf2, acc2, la2, KC, VC)                                       \
        TILE_OP(qf3, acc3, la3, KC, VC)

        for (int tt = 0; tt < 32; tt += 4) {
            s16x4 kc, vc;
            kc = kr0; vc = vr0;
            if (tt + 4 < 32) { kr0 = *(const s16x4*)(kb + ((tt + 4) << 8)); vr0 = *(const s16x4*)(vb + ((tt + 4) << 8)); }
            ATTN_BODY(kc, vc)
            kc = kr1; vc = vr1;
            if (tt + 5 < 32) { kr1 = *(const s16x4*)(kb + ((tt + 5) << 8)); vr1 = *(const s16x4*)(vb + ((tt + 5) << 8)); }
            ATTN_BODY(kc, vc)
            kc = kr2; vc = vr2;
            if (tt + 6 < 32) { kr2 = *(const s16x4*)(kb + ((tt + 6) << 8)); vr2 = *(const s16x4*)(vb + ((tt + 6) << 8)); }
            ATTN_BODY(kc, vc)
            kc = kr3; vc = vr3;
            if (tt + 7 < 32) { kr3 = *(const s16x4*)(kb + ((tt + 7) << 8)); vr3 = *(const s16x4*)(vb + ((tt + 7) << 8)); }
            ATTN_BODY(kc, vc)
        }
#undef ATTN_BODY
#undef TILE_OP

        *(f32x4*)&accl[(((w << 2) + 0) << 8) + (lane << 2)] = acc0;
        *(f32x4*)&accl[(((w << 2) + 1) << 8) + (lane << 2)] = acc1;
        *(f32x4*)&accl[(((w << 2) + 2) << 8) + (lane << 2)] = acc2;
        *(f32x4*)&accl[(((w << 2) + 3) << 8) + (lane << 2)] = acc3;
        if (g == 0) {
            lred[(((w << 2) + 0) << 4) + c] = la0[0];
            lred[(((w << 2) + 1) << 4) + c] = la1[0];
            lred[(((w << 2) + 2) << 4) + c] = la2[0];
            lred[(((w << 2) + 3) << 4) + c] = la3[0];
        }
        __syncthreads();

        if (tid < 64) {
            const int tile = tid >> 4, cc2 = tid & 15;
            float s = 0.f;
            #pragma unroll
            for (int w2 = 0; w2 < 8; ++w2) s += lred[(((w2 << 2) + tile) << 4) + cc2];
            ltot[tid] = 1.0f / s;
        }
        __syncthreads();

        #pragma unroll
        for (int pass = 0; pass < 2; ++pass) {
            const int s = tid + (pass << 9);         // < 1024
            const int tile = s >> 8, elem = s & 255;
            const int lane2 = elem >> 2, ii = elem & 3;
            const int c2 = lane2 & 15, g2 = lane2 >> 4;
            const int e = (g2 << 2) + ii;
            float ssum = 0.f;
            #pragma unroll
            for (int w2 = 0; w2 < 8; ++w2) ssum += accl[(((w2 << 2) + tile) << 8) + elem];
            const int qt = qt0 + tile;
            const float res = (float)vT_t[(((h << 8) + qt) << 8) + (e << 4) + c2];
            const float val = ssum * ltot[(tile << 4) + c2] + res;
            voutT[((qt >> 1) << 11) + (((h << 4) + e) << 5) + ((qt & 1) << 4) + c2] = (__bf16)val;
        }
    }
    grid_barrier(bars + 16, 256);

    // ------------------------------------------------------------ P3: ds GEMM
    {
        const int rb = blockIdx.x >> 3;              // 0..31  (64-row block)
        const int ks = blockIdx.x & 7;               // K chunk of 512
        const int rsub = w >> 1, kh = w & 1;
        const int r0 = (rb << 6) + (rsub << 4);
        const int kb0 = (ks << 9) + (kh << 8);
        const float* wdrow = Wd + (r0 + c) * 4096 + kb0;

        f32x4 acc0 = {0.f,0.f,0.f,0.f}, acc1 = acc0, acc2 = acc0, acc3 = acc0;
        #pragma unroll
        for (int it = 0; it < 8; ++it) {
            const int k0 = it << 5;
            bf16x8 af = cvt8(*(const float4*)(wdrow + k0 + (g << 3)),
                             *(const float4*)(wdrow + k0 + (g << 3) + 4));
            const __bf16* bt = voutT + (((kb0 + k0) >> 5) << 11) + (g << 3);
            bf16x8 b0 = *(const bf16x8*)(bt + ((c     ) << 5));
            bf16x8 b1 = *(const bf16x8*)(bt + ((c + 16) << 5));
            bf16x8 b2 = *(const bf16x8*)(bt + ((c + 32) << 5));
            bf16x8 b3 = *(const bf16x8*)(bt + ((c + 48) << 5));
            acc0 = MFMA32(af, b0, acc0);
            acc1 = MFMA32(af, b1, acc1);
            acc2 = MFMA32(af, b2, acc2);
            acc3 = MFMA32(af, b3, acc3);
        }

        float* dsred = (float*)arena;                // [4][4][64][4] = 16 KB
        if (kh == 1) {
            *(f32x4*)&dsred[(((rsub << 2) + 0) << 8) + (lane << 2)] = acc0;
            *(f32x4*)&dsred[(((rsub << 2) + 1) << 8) + (lane << 2)] = acc1;
            *(f32x4*)&dsred[(((rsub << 2) + 2) << 8) + (lane << 2)] = acc2;
            *(f32x4*)&dsred[(((rsub << 2) + 3) << 8) + (lane << 2)] = acc3;
        }
        __syncthreads();
        if (kh == 0) {
            acc0 += *(const f32x4*)&dsred[(((rsub << 2) + 0) << 8) + (lane << 2)];
            acc1 += *(const f32x4*)&dsred[(((rsub << 2) + 1) << 8) + (lane << 2)];
            acc2 += *(const f32x4*)&dsred[(((rsub << 2) + 2) << 8) + (lane << 2)];
            acc3 += *(const f32x4*)&dsred[(((rsub << 2) + 3) << 8) + (lane << 2)];
            float* pbase = partial + (((ks << 11) + r0) << 6);
            #pragma unroll
            for (int i = 0; i < 4; ++i) {
                const int r = (g << 2) + i;
                pbase[(r << 6) +      c] = acc0[i];
                pbase[(r << 6) + 16 + c] = acc1[i];
                pbase[(r << 6) + 32 + c] = acc2[i];
                pbase[(r << 6) + 48 + c] = acc3[i];
            }
        }
    }
    grid_barrier(bars + 32, 256);

    // ------------------------------------------------------------ P4: reduce
    {
        const int idx = (blockIdx.x << 9) + tid;     // < 131072
        float s = bd[idx >> 6];
        #pragma unroll
        for (int k = 0; k < 8; ++k) s += partial[(k << 17) + idx];
        out[idx] = s;
    }
}

// ============================================================================
extern "C" void kernel_launch(void* const* d_in, const int* in_sizes, int n_in,
                              void* d_out, int out_size, void* d_ws, size_t ws_size,
                              hipStream_t stream)
{
    const float* x  = (const float*)d_in[0];
    const float* Wq = (const float*)d_in[1];
    const float* bq = (const float*)d_in[2];
    const float* Wk = (const float*)d_in[3];
    const float* bk = (const float*)d_in[4];
    const float* Wv = (const float*)d_in[5];
    const float* bv = (const float*)d_in[6];
    const float* Wd = (const float*)d_in[7];
    const float* bd = (const float*)d_in[8];
    float* out = (float*)d_out;

    char* ws = (char*)d_ws;
    __bf16* q_bf   = (__bf16*)(ws);                  // 512 KB [4][4096][16]
    __bf16* k_bf   = (__bf16*)(ws + (1u << 19));     // 512 KB [4][4096][16]
    __bf16* vT_t   = (__bf16*)(ws + (2u << 19));     // 512 KB [4][256][16][16]
    __bf16* voutT  = (__bf16*)(ws + (3u << 19));     // 512 KB [128][64][32]
    float*  partial = (float*)(ws + (4u << 19));     // 4 MB  [8][2048][64]
    unsigned* bars  = (unsigned*)(ws + (12u << 19)); // barrier counters

    hipMemsetAsync(bars, 0, 256, stream);
    fused_kernel<<<dim3(256), dim3(512), 0, stream>>>(
        x, Wq, bq, Wk, bk, Wv, bv, Wd, bd,
        q_bf, k_bf, vT_t, voutT, partial, bars, out);
}

// Round 8
// 51.106 us; speedup vs baseline: 2.4151x; 2.1157x over previous
//
#include <hip/hip_runtime.h>

// ---- types ----
typedef __bf16 bf16x8 __attribute__((ext_vector_type(8)));
typedef __bf16 bf16x4 __attribute__((ext_vector_type(4)));
typedef short s16x4 __attribute__((ext_vector_type(4)));
typedef float f32x4 __attribute__((ext_vector_type(4)));

#define MFMA32(a, b, c) __builtin_amdgcn_mfma_f32_16x16x32_bf16((a), (b), (c), 0, 0, 0)
#define MFMA16(a, b, c) __builtin_amdgcn_mfma_f32_16x16x16bf16_1k((a), (b), (c), 0, 0, 0)

// q pre-scale: 1/sqrt(E)=0.25 folded with 1/ln(2) so attn uses exp2 directly.
#define QSCALE 0.36067376022224085f

static __device__ inline bf16x8 cvt8(float4 a, float4 b) {
    bf16x8 r;
    r[0] = (__bf16)a.x; r[1] = (__bf16)a.y; r[2] = (__bf16)a.z; r[3] = (__bf16)a.w;
    r[4] = (__bf16)b.x; r[5] = (__bf16)b.y; r[6] = (__bf16)b.z; r[7] = (__bf16)b.w;
    return r;
}

// ============================================================================
// K1: fused QKV projection, K-split by wave + LDS reduce.  (proven R5 form)
// grid = 256 rowgroups x 3 which; block = 256 (4 waves).
// q stored [h][n][16] bf16 pre-scaled; k stored [h][n][16];
// v stored TILED: [h][ntile 256][e 16][kv 16]  (contiguous A-fragments).
// ============================================================================
__global__ __launch_bounds__(256) void qkv_kernel(
    const float* __restrict__ x,
    const float* __restrict__ Wq, const float* __restrict__ bq,
    const float* __restrict__ Wk, const float* __restrict__ bk,
    const float* __restrict__ Wv, const float* __restrict__ bv,
    __bf16* __restrict__ q_bf, __bf16* __restrict__ k_bf,
    __bf16* __restrict__ vT_t)
{
    __shared__ float red[4 * 4 * 64 * 4];    // [wave][head][lane][4] = 16 KB

    const int rg = blockIdx.x & 255;
    const int which = blockIdx.x >> 8;       // 0=q 1=k 2=v
    const int w  = threadIdx.x >> 6;
    const int lane = threadIdx.x & 63;
    const int c = lane & 15;
    const int g = lane >> 4;
    const int row0 = rg << 4;

    const float* Wsel = (which == 0) ? Wq : (which == 1) ? Wk : Wv;
    const float* bsel = (which == 0) ? bq : (which == 1) ? bk : bv;

    const float* xrow = x + (row0 + c) * 640 + w * 160;
    const float* wr0 = Wsel + (0 * 16 + c) * 640 + w * 160;
    const float* wr1 = Wsel + (1 * 16 + c) * 640 + w * 160;
    const float* wr2 = Wsel + (2 * 16 + c) * 640 + w * 160;
    const float* wr3 = Wsel + (3 * 16 + c) * 640 + w * 160;

    f32x4 acc0 = {0.f,0.f,0.f,0.f}, acc1 = acc0, acc2 = acc0, acc3 = acc0;
    #pragma unroll 5
    for (int k0 = 0; k0 < 160; k0 += 32) {
        const int kk = k0 + (g << 3);
        bf16x8 af = cvt8(*(const float4*)(xrow + kk), *(const float4*)(xrow + kk + 4));
        bf16x8 b0 = cvt8(*(const float4*)(wr0 + kk), *(const float4*)(wr0 + kk + 4));
        bf16x8 b1 = cvt8(*(const float4*)(wr1 + kk), *(const float4*)(wr1 + kk + 4));
        bf16x8 b2 = cvt8(*(const float4*)(wr2 + kk), *(const float4*)(wr2 + kk + 4));
        bf16x8 b3 = cvt8(*(const float4*)(wr3 + kk), *(const float4*)(wr3 + kk + 4));
        acc0 = MFMA32(af, b0, acc0);
        acc1 = MFMA32(af, b1, acc1);
        acc2 = MFMA32(af, b2, acc2);
        acc3 = MFMA32(af, b3, acc3);
    }

    *(f32x4*)&red[((((w << 2) + 0) << 6) + lane) << 2] = acc0;
    *(f32x4*)&red[((((w << 2) + 1) << 6) + lane) << 2] = acc1;
    *(f32x4*)&red[((((w << 2) + 2) << 6) + lane) << 2] = acc2;
    *(f32x4*)&red[((((w << 2) + 3) << 6) + lane) << 2] = acc3;
    __syncthreads();

    // finalize: wave h (= threadIdx.x>>6) owns head h
    const int h = threadIdx.x >> 6;
    f32x4 sum = {0.f,0.f,0.f,0.f};
    #pragma unroll
    for (int ww = 0; ww < 4; ++ww)
        sum += *(const f32x4*)&red[((((ww << 2) + h) << 6) + lane) << 2];

    const float bias = bsel[(h << 4) + c];
    if (which == 2) {
        bf16x4 vv;
        #pragma unroll
        for (int i = 0; i < 4; ++i) vv[i] = (__bf16)(sum[i] + bias);
        // [h][tile=rg][e=c][kv=4g+i]
        *(bf16x4*)(vT_t + ((((h << 8) + rg) << 8) + (c << 4) + (g << 2))) = vv;
    } else {
        #pragma unroll
        for (int i = 0; i < 4; ++i) {
            const int n = row0 + (g << 2) + i;
            const float val = sum[i] + bias;
            if (which == 0) q_bf[(((h << 12) + n) << 4) + c] = (__bf16)(val * QSCALE);
            else            k_bf[(((h << 12) + n) << 4) + c] = (__bf16)val;
        }
    }
}

// ============================================================================
// K2: flash attention with IN-BLOCK KV-split + combine (proven R5 form),
// plus 128 Wd-WARMING blocks (blockIdx >= 512) that stream Wd into L3
// concurrently (attn is VALU/exp-bound; warm rides free HBM BW).
// Compute blocks: grid 512 (h*128+qp); block 512 (8 waves).  Block owns
// 2 q-tiles; wave w streams kv chunk [w*512,(w+1)*512) with a depth-4
// statically-indexed register pipeline.  No max-tracking (scores bounded),
// exp2 path, lsum via ones-MFMA.  In-block combine + residual -> tiled voutT.
// ============================================================================
__global__ __launch_bounds__(512) void attn_kernel(
    const __bf16* __restrict__ q_bf, const __bf16* __restrict__ k_bf,
    const __bf16* __restrict__ vT_t, __bf16* __restrict__ voutT,
    const float* __restrict__ Wd, float* __restrict__ warm_sink)
{
    __shared__ float accl[8 * 2 * 256];   // [wave][tile][lane*4+i] = 16KB
    __shared__ float lred[8 * 2 * 16];    // [wave][tile][c]
    __shared__ float ltot[2 * 16];

    const int bx = blockIdx.x;
    const int tid = threadIdx.x;

    if (bx >= 512) {
        // ---- Wd warmer: 128 blocks x 512 thr x 32 float4 = 33.5 MB -> L3
        const int wb = bx - 512;
        const float4* src = (const float4*)Wd;
        float4 a = {0.f, 0.f, 0.f, 0.f};
        #pragma unroll 8
        for (int i = 0; i < 32; ++i) {
            float4 v = src[(i << 16) + (wb << 9) + tid];
            a.x += v.x; a.y += v.y; a.z += v.z; a.w += v.w;
        }
        const float s = (a.x + a.y) + (a.z + a.w);
        if (s == 1234.56789f) warm_sink[(wb << 9) + tid] = s;  // DCE guard
        return;
    }

    const int qp = bx & 127;
    const int h  = bx >> 7;
    const int w = tid >> 6;
    const int lane = tid & 63;
    const int c = lane & 15;
    const int g = lane >> 4;
    const int qbase = qp << 5;

    const s16x4 qf0 = *(const s16x4*)(q_bf + (((h << 12) + qbase + c) << 4) + (g << 2));
    const s16x4 qf1 = *(const s16x4*)(q_bf + (((h << 12) + qbase + 16 + c) << 4) + (g << 2));

    const __bf16* kb = k_bf + (((h << 12) + (w << 9)) << 4) + (c << 4) + (g << 2);
    const __bf16* vb = vT_t + (((h << 8) + (w << 5)) << 8) + (c << 4) + (g << 2);

    bf16x4 one4;
    #pragma unroll
    for (int j = 0; j < 4; ++j) one4[j] = (__bf16)1.0f;
    const s16x4 onesf = __builtin_bit_cast(s16x4, one4);

    const f32x4 z = {0.f, 0.f, 0.f, 0.f};
    f32x4 acc0 = z, acc1 = z, la0 = z, la1 = z;

    s16x4 kr0 = *(const s16x4*)(kb);
    s16x4 kr1 = *(const s16x4*)(kb + 256);
    s16x4 kr2 = *(const s16x4*)(kb + 512);
    s16x4 kr3 = *(const s16x4*)(kb + 768);
    s16x4 vr0 = *(const s16x4*)(vb);
    s16x4 vr1 = *(const s16x4*)(vb + 256);
    s16x4 vr2 = *(const s16x4*)(vb + 512);
    s16x4 vr3 = *(const s16x4*)(vb + 768);

#define ATTN_BODY(KC, VC)                                                     \
    {                                                                         \
        f32x4 s0 = MFMA16((KC), qf0, z);                                      \
        f32x4 s1 = MFMA16((KC), qf1, z);                                      \
        float p00 = __builtin_amdgcn_exp2f(s0[0]);                            \
        float p01 = __builtin_amdgcn_exp2f(s0[1]);                            \
        float p02 = __builtin_amdgcn_exp2f(s0[2]);                            \
        float p03 = __builtin_amdgcn_exp2f(s0[3]);                            \
        float p10 = __builtin_amdgcn_exp2f(s1[0]);                            \
        float p11 = __builtin_amdgcn_exp2f(s1[1]);                            \
        float p12 = __builtin_amdgcn_exp2f(s1[2]);                            \
        float p13 = __builtin_amdgcn_exp2f(s1[3]);                            \
        bf16x4 pb0, pb1;                                                      \
        pb0[0] = (__bf16)p00; pb0[1] = (__bf16)p01;                           \
        pb0[2] = (__bf16)p02; pb0[3] = (__bf16)p03;                           \
        pb1[0] = (__bf16)p10; pb1[1] = (__bf16)p11;                           \
        pb1[2] = (__bf16)p12; pb1[3] = (__bf16)p13;                           \
        const s16x4 pf0 = __builtin_bit_cast(s16x4, pb0);                     \
        const s16x4 pf1 = __builtin_bit_cast(s16x4, pb1);                     \
        la0 = MFMA16(onesf, pf0, la0);                                        \
        la1 = MFMA16(onesf, pf1, la1);                                        \
        acc0 = MFMA16((VC), pf0, acc0);                                       \
        acc1 = MFMA16((VC), pf1, acc1);                                       \
    }

    for (int tt = 0; tt < 32; tt += 4) {
        s16x4 kc, vc;
        kc = kr0; vc = vr0;
        if (tt + 4 < 32) { kr0 = *(const s16x4*)(kb + ((tt + 4) << 8)); vr0 = *(const s16x4*)(vb + ((tt + 4) << 8)); }
        ATTN_BODY(kc, vc)
        kc = kr1; vc = vr1;
        if (tt + 5 < 32) { kr1 = *(const s16x4*)(kb + ((tt + 5) << 8)); vr1 = *(const s16x4*)(vb + ((tt + 5) << 8)); }
        ATTN_BODY(kc, vc)
        kc = kr2; vc = vr2;
        if (tt + 6 < 32) { kr2 = *(const s16x4*)(kb + ((tt + 6) << 8)); vr2 = *(const s16x4*)(vb + ((tt + 6) << 8)); }
        ATTN_BODY(kc, vc)
        kc = kr3; vc = vr3;
        if (tt + 7 < 32) { kr3 = *(const s16x4*)(kb + ((tt + 7) << 8)); vr3 = *(const s16x4*)(vb + ((tt + 7) << 8)); }
        ATTN_BODY(kc, vc)
    }
#undef ATTN_BODY

    // wave partials -> LDS
    *(f32x4*)&accl[(((w << 1) + 0) << 8) + (lane << 2)] = acc0;
    *(f32x4*)&accl[(((w << 1) + 1) << 8) + (lane << 2)] = acc1;
    if (g == 0) {
        lred[(((w << 1) + 0) << 4) + c] = la0[0];
        lred[(((w << 1) + 1) << 4) + c] = la1[0];
    }
    __syncthreads();

    if (tid < 32) {
        const int tile = tid >> 4, cc = tid & 15;
        float s = 0.f;
        #pragma unroll
        for (int w2 = 0; w2 < 8; ++w2) s += lred[(((w2 << 1) + tile) << 4) + cc];
        ltot[(tile << 4) + cc] = 1.0f / s;
    }
    __syncthreads();

    // block combine + residual + tiled store
    {
        const int tile = tid >> 8;
        const int elem = tid & 255;
        const int lane2 = elem >> 2, i = elem & 3;
        const int c2 = lane2 & 15, g2 = lane2 >> 4;
        const int e = (g2 << 2) + i;
        float s = 0.f;
        #pragma unroll
        for (int w2 = 0; w2 < 8; ++w2) s += accl[(((w2 << 1) + tile) << 8) + elem];
        const int qt = (qp << 1) + tile;
        const float res = (float)vT_t[((((h << 8) + qt) << 8)) + (e << 4) + c2];
        const float val = s * ltot[(tile << 4) + c2] + res;
        voutT[(qp << 11) + (((h << 4) + e) << 5) + (tile << 4) + c2] = (__bf16)val;
    }
}

// ============================================================================
// K3: downsample GEMM, split-K x16 -> partial[16][2048][64] (no atomics).
// grid = 512 (32 rowblocks x 16 ks), block = 256.  Wd now L3-warm.
// B read from tiled voutT: fully coalesced fragments.
// ============================================================================
__global__ __launch_bounds__(256) void dsgemm_kernel(
    const float* __restrict__ Wd, const __bf16* __restrict__ voutT,
    float* __restrict__ partial)
{
    const int rb = blockIdx.x & 31;
    const int ks = blockIdx.x >> 5;      // 0..15
    const int w  = threadIdx.x >> 6;
    const int lane = threadIdx.x & 63;
    const int c = lane & 15;
    const int g = lane >> 4;
    const int rowbase = rb * 64 + w * 16;
    const float* wdrow = Wd + (rowbase + c) * 4096;

    f32x4 acc0 = {0.f,0.f,0.f,0.f}, acc1 = acc0, acc2 = acc0, acc3 = acc0;
    #pragma unroll
    for (int it = 0; it < 8; ++it) {
        const int k0 = ks * 256 + it * 32;
        bf16x8 af = cvt8(*(const float4*)(wdrow + k0 + (g << 3)),
                         *(const float4*)(wdrow + k0 + (g << 3) + 4));
        const __bf16* bt = voutT + ((k0 >> 5) << 11) + (g << 3);
        bf16x8 b0 = *(const bf16x8*)(bt + ((c     ) << 5));
        bf16x8 b1 = *(const bf16x8*)(bt + ((c + 16) << 5));
        bf16x8 b2 = *(const bf16x8*)(bt + ((c + 32) << 5));
        bf16x8 b3 = *(const bf16x8*)(bt + ((c + 48) << 5));
        acc0 = MFMA32(af, b0, acc0);
        acc1 = MFMA32(af, b1, acc1);
        acc2 = MFMA32(af, b2, acc2);
        acc3 = MFMA32(af, b3, acc3);
    }

    float* pbase = partial + (((ks << 11) + rowbase) << 6);
    #pragma unroll
    for (int i = 0; i < 4; ++i) {
        const int r = (g << 2) + i;
        pbase[(r << 6) +      c] = acc0[i];
        pbase[(r << 6) + 16 + c] = acc1[i];
        pbase[(r << 6) + 32 + c] = acc2[i];
        pbase[(r << 6) + 48 + c] = acc3[i];
    }
}

// ============================================================================
// K4: reduce 16 split-K partials + bias -> out f32 [2048][64], float4-wide.
// grid = 128 x 256; thread t handles float4 #t.
// ============================================================================
__global__ __launch_bounds__(256) void reduce_kernel(
    const float* __restrict__ partial, const float* __restrict__ bd,
    float* __restrict__ out)
{
    const int i4 = blockIdx.x * 256 + threadIdx.x;   // < 32768
    const float b = bd[i4 >> 4];                     // 16 float4 per out-row
    f32x4 s = {b, b, b, b};
    #pragma unroll
    for (int k = 0; k < 16; ++k)
        s += *(const f32x4*)(partial + (k << 17) + (i4 << 2));
    *(f32x4*)(out + (i4 << 2)) = s;
}

// ============================================================================
extern "C" void kernel_launch(void* const* d_in, const int* in_sizes, int n_in,
                              void* d_out, int out_size, void* d_ws, size_t ws_size,
                              hipStream_t stream)
{
    const float* x  = (const float*)d_in[0];
    const float* Wq = (const float*)d_in[1];
    const float* bq = (const float*)d_in[2];
    const float* Wk = (const float*)d_in[3];
    const float* bk = (const float*)d_in[4];
    const float* Wv = (const float*)d_in[5];
    const float* bv = (const float*)d_in[6];
    const float* Wd = (const float*)d_in[7];
    const float* bd = (const float*)d_in[8];
    float* out = (float*)d_out;

    char* ws = (char*)d_ws;
    __bf16* q_bf   = (__bf16*)(ws);                  // 512 KB [4][4096][16]
    __bf16* k_bf   = (__bf16*)(ws + (1u << 19));     // 512 KB [4][4096][16]
    __bf16* vT_t   = (__bf16*)(ws + (2u << 19));     // 512 KB [4][256][16][16]
    __bf16* voutT  = (__bf16*)(ws + (3u << 19));     // 512 KB [128][64][32]
    float*  partial = (float*)(ws + (4u << 19));     // 8 MB  [16][2048][64]

    qkv_kernel<<<dim3(768), dim3(256), 0, stream>>>(x, Wq, bq, Wk, bk, Wv, bv,
                                                    q_bf, k_bf, vT_t);
    attn_kernel<<<dim3(640), dim3(512), 0, stream>>>(q_bf, k_bf, vT_t, voutT,
                                                     Wd, partial);
    dsgemm_kernel<<<dim3(512), dim3(256), 0, stream>>>(Wd, voutT, partial);
    reduce_kernel<<<dim3(128), dim3(256), 0, stream>>>(partial, bd, out);
}